// Round 1
// baseline (95.797 us; speedup 1.0000x reference)
//
#include <hip/hip_runtime.h>

// Problem shape from reference setup_inputs(): fixed B=256, L=512, D=64, fp32.
constexpr int Bn = 256;
constexpr int Ln = 512;
constexpr int Dn = 64;
constexpr float EPS_LOG = 1e-7f;
constexpr float EPS_COS = 1e-8f;

// One block per batch sample b. 1024 threads = 16 waves.
// Key insight: reference only consumes wnl[b,b] (diagonal), so only the
// cosine-sim row l=b is needed per sample: cos(emb[b,b,:], emb[b,k,:]) for all k.
// Lane = dim (D=64 == wave width): one coalesced 256B row load per k per wave,
// butterfly-reduce dot and norm^2 across the 64 lanes.
__global__ __launch_bounds__(1024) void wnl_kernel(
    const float* __restrict__ emb,     // (B, L, D)
    const float* __restrict__ probs,   // (B, L)
    const float* __restrict__ labels,  // (B, L)
    float* __restrict__ out)           // scalar
{
    const int b    = blockIdx.x;
    const int tid  = threadIdx.x;
    const int wave = tid >> 6;
    const int lane = tid & 63;
    constexpr int NW = 1024 / 64;  // 16 waves

    __shared__ float s_q[Dn];
    __shared__ float s_lab[Ln];
    __shared__ float s_max[NW];
    __shared__ float s_pos[NW];
    __shared__ float s_lng[NW];

    const float* eb = emb    + (size_t)b * Ln * Dn;
    const float* pb = probs  + (size_t)b * Ln;
    const float* lb = labels + (size_t)b * Ln;

    // stage q = emb[b, b, :] (valid: b < 256 <= L) and this sample's labels
    if (tid < Dn) s_q[tid]  = eb[(size_t)b * Dn + tid];
    if (tid < Ln) s_lab[tid] = lb[tid];
    __syncthreads();

    const float qd = s_q[lane];
    float nq = qd * qd;
    #pragma unroll
    for (int off = 32; off; off >>= 1) nq += __shfl_xor(nq, off);
    const float norm_q = sqrtf(nq);

    // row_max over k of relu(cos) * labels[b,k]; all terms >= 0 so init 0
    float maxv = 0.f;
    for (int k = wave; k < Ln; k += NW) {
        float v = eb[(size_t)k * Dn + lane];  // coalesced: 64 lanes x 4B
        float d = qd * v;
        float n = v * v;
        #pragma unroll
        for (int off = 32; off; off >>= 1) {
            d += __shfl_xor(d, off);
            n += __shfl_xor(n, off);
        }
        float denom = fmaxf(norm_q * sqrtf(n), EPS_COS);
        float cs    = d / denom;
        float m     = fmaxf(cs, 0.f) * s_lab[k];  // relu (theta=0) then mask
        maxv = fmaxf(maxv, m);
    }

    // per-sample prob sums: pos = sum labels*log(p+eps); lng = sum log(1-(p+eps))
    float pos = 0.f, lng = 0.f;
    if (tid < Ln) {
        float p = pb[tid] + EPS_LOG;
        pos = s_lab[tid] * logf(p);
        lng = logf(1.f - p);
    }
    #pragma unroll
    for (int off = 32; off; off >>= 1) {
        pos += __shfl_xor(pos, off);
        lng += __shfl_xor(lng, off);
    }

    if (lane == 0) { s_max[wave] = maxv; s_pos[wave] = pos; s_lng[wave] = lng; }
    __syncthreads();

    if (tid == 0) {
        float rm = 0.f, P = 0.f, LN = 0.f;
        #pragma unroll
        for (int w = 0; w < NW; ++w) {
            rm = fmaxf(rm, s_max[w]);
            P += s_pos[w];
            LN += s_lng[w];
        }
        // weak-negative weight only if labels[b,b] == 0
        float wnl = (s_lab[b] == 0.f) ? rm : 0.f;
        // loss contribution of this sample, pre-scaled by 1/B
        float contrib = (-P - wnl * LN) * (1.f / (float)Bn);
        atomicAdd(out, contrib);
    }
}

extern "C" void kernel_launch(void* const* d_in, const int* in_sizes, int n_in,
                              void* d_out, int out_size, void* d_ws, size_t ws_size,
                              hipStream_t stream) {
    const float* emb    = (const float*)d_in[0];
    const float* probs  = (const float*)d_in[1];
    const float* labels = (const float*)d_in[2];
    float* out = (float*)d_out;

    // d_out is poisoned to 0xAA before every timed launch — zero it (capture-safe)
    hipMemsetAsync(out, 0, out_size * sizeof(float), stream);
    wnl_kernel<<<Bn, 1024, 0, stream>>>(emb, probs, labels, out);
}

// Round 2
// 78.734 us; speedup vs baseline: 1.2167x; 1.2167x over previous
//
#include <hip/hip_runtime.h>

// Problem shape from reference setup_inputs(): fixed B=256, L=512, D=64, fp32.
constexpr int Bn = 256;
constexpr int Ln = 512;
constexpr int Dn = 64;
constexpr float EPS_LOG = 1e-7f;
constexpr float EPS_COS = 1e-8f;

// One block per batch sample b (grid=256 -> 1 block/CU). 1024 threads = 16 waves.
// Reference only consumes wnl[b,b], so only cosine row l=b is needed per sample.
//
// Layout: each 16-lane subgroup owns one row k; lane i of the subgroup loads
// float4 emb[b][k][4i..4i+3]. A wave's 4 subgroups cover 4 CONSECUTIVE rows,
// so each wave-load is one contiguous 1 KB burst (perfect coalescing).
// Dot/norm reduced over 16 lanes in 4 shuffle steps (vs 6 for wave-wide).
__global__ __launch_bounds__(1024) void wnl_kernel(
    const float* __restrict__ emb,     // (B, L, D)
    const float* __restrict__ probs,   // (B, L)
    const float* __restrict__ labels,  // (B, L)
    float* __restrict__ out)           // scalar
{
    const int b    = blockIdx.x;
    const int tid  = threadIdx.x;
    const int wave = tid >> 6;         // 0..15
    const int lane = tid & 63;
    const int sub  = lane >> 4;        // 0..3  : row within the wave's group
    const int i16  = lane & 15;        // 0..15 : which float4 chunk of D
    constexpr int NW = 1024 / 64;      // 16 waves

    __shared__ float s_lab[Ln];
    __shared__ float s_max[NW];
    __shared__ float s_pos[NW];
    __shared__ float s_lng[NW];

    const float* eb = emb    + (size_t)b * Ln * Dn;
    const float* pb = probs  + (size_t)b * Ln;
    const float* lb = labels + (size_t)b * Ln;

    if (tid < Ln) s_lab[tid] = lb[tid];

    // q = emb[b, b, :] (b < 256 <= L). Each lane grabs its 16B chunk
    // (all 4 subgroups read the same 16B -> broadcast).
    const float4 qv = *(const float4*)(eb + (size_t)b * Dn + 4 * i16);

    // ||q||^2 : per-lane partial over its 4 dims, reduce across the 16-lane
    // subgroup (each subgroup covers all 64 dims exactly once).
    float nq = qv.x * qv.x + qv.y * qv.y + qv.z * qv.z + qv.w * qv.w;
    #pragma unroll
    for (int off = 1; off < 16; off <<= 1) nq += __shfl_xor(nq, off);
    const float norm_q = sqrtf(nq);

    // Row sweep: 16 waves x 4 rows/iter = 64 rows per block-iteration; 8 iters.
    float maxv = 0.f;
    #pragma unroll
    for (int it = 0; it < Ln / (NW * 4); ++it) {
        const int k = it * (NW * 4) + wave * 4 + sub;
        const float4 v = *(const float4*)(eb + (size_t)k * Dn + 4 * i16);
        float d = qv.x * v.x + qv.y * v.y + qv.z * v.z + qv.w * v.w;
        float n = v.x * v.x + v.y * v.y + v.z * v.z + v.w * v.w;
        #pragma unroll
        for (int off = 1; off < 16; off <<= 1) {
            d += __shfl_xor(d, off);
            n += __shfl_xor(n, off);
        }
        // all 16 lanes of the subgroup now hold full dot & norm^2 for row k
        float denom = fmaxf(norm_q * sqrtf(n), EPS_COS);
        float cs    = __fdividef(d, denom);
        float m     = fmaxf(cs, 0.f) * s_lab[k];  // relu (theta=0), mask
        maxv = fmaxf(maxv, m);
    }
    // combine the 4 subgroups' maxima across the wave
    maxv = fmaxf(maxv, __shfl_xor(maxv, 16));
    maxv = fmaxf(maxv, __shfl_xor(maxv, 32));

    // per-sample prob sums: pos = sum labels*log(p+eps); lng = sum log(1-(p+eps))
    float pos = 0.f, lng = 0.f;
    if (tid < Ln) {
        float p = pb[tid] + EPS_LOG;
        pos = s_lab[tid] * __logf(p);
        lng = __logf(1.f - p);
    }
    #pragma unroll
    for (int off = 32; off; off >>= 1) {
        pos += __shfl_xor(pos, off);
        lng += __shfl_xor(lng, off);
    }

    if (lane == 0) { s_max[wave] = maxv; s_pos[wave] = pos; s_lng[wave] = lng; }
    __syncthreads();

    if (tid == 0) {
        float rm = 0.f, P = 0.f, LN = 0.f;
        #pragma unroll
        for (int w = 0; w < NW; ++w) {
            rm = fmaxf(rm, s_max[w]);
            P += s_pos[w];
            LN += s_lng[w];
        }
        float wnl = (s_lab[b] == 0.f) ? rm : 0.f;
        float contrib = (-P - wnl * LN) * (1.f / (float)Bn);
        atomicAdd(out, contrib);
    }
}

extern "C" void kernel_launch(void* const* d_in, const int* in_sizes, int n_in,
                              void* d_out, int out_size, void* d_ws, size_t ws_size,
                              hipStream_t stream) {
    const float* emb    = (const float*)d_in[0];
    const float* probs  = (const float*)d_in[1];
    const float* labels = (const float*)d_in[2];
    float* out = (float*)d_out;

    // d_out is poisoned to 0xAA before every timed launch — zero it (capture-safe)
    hipMemsetAsync(out, 0, out_size * sizeof(float), stream);
    wnl_kernel<<<Bn, 1024, 0, stream>>>(emb, probs, labels, out);
}